// Round 1
// baseline (60.745 us; speedup 1.0000x reference)
//
#include <hip/hip_runtime.h>

#define A_ 4096
#define M_ 64
#define Q_ 64
#define H_ 128

// ---------------------------------------------------------------------------
// Kernel 1: one block per atom.
//  - stage W0[Z[n]] (64x128 f32) into LDS with stride 129 (bank-conflict-free
//    for both h-major and q-major reads)
//  - wave0/1: MLP forward -> de_da ; wave2: rij^2 * neighbor_mask (independent)
//  - de_dq[q] = sum_h de_da[h] * W0[q][h]
//  - 192 threads: per-(m,c) dot of de_dq against gradients row (float4 x16)
//  - deterministic per-block reduction -> partials[n][3]
// ---------------------------------------------------------------------------
__global__ __launch_bounds__(256) void tnep_main(
    const float* __restrict__ desc,     // [A,Q]
    const float* __restrict__ grad,     // [A,M,3,Q]
    const int*   __restrict__ gidx,     // [A,M]
    const float* __restrict__ pos,      // [A,3]
    const int*   __restrict__ Zt,       // [A]
    const float* __restrict__ box,      // [3,3]
    const float* __restrict__ amask,    // [A]
    const float* __restrict__ nmask,    // [A,M]
    const float* __restrict__ W0,       // [NT,Q,H]
    const float* __restrict__ b0,       // [NT,H]
    const float* __restrict__ W1,       // [NT,H]
    float* __restrict__ partials)       // [A,3]
{
    __shared__ __align__(16) float W0s[Q_ * 129];
    __shared__ __align__(16) float desc_s[Q_];
    __shared__ float deda_s[H_];
    __shared__ __align__(16) float dedq_s[Q_];
    __shared__ float rij2m_s[M_];       // rij^2 * neighbor_mask
    __shared__ float cred[3][M_];

    const int n = blockIdx.x;
    const int t = threadIdx.x;
    const int z = Zt[n];
    const float am = amask[n];

    // stage W0[z] -> LDS (padded stride 129), coalesced global reads
    const float* W0z = W0 + (size_t)z * (Q_ * H_);
    for (int idx = t; idx < Q_ * H_; idx += 256) {
        int q = idx >> 7;        // / 128
        int h = idx & 127;
        W0s[q * 129 + h] = W0z[idx];
    }
    if (t < Q_) desc_s[t] = desc[n * Q_ + t];
    __syncthreads();

    // --- phase 2 (waves 0,1): MLP forward + dtanh * W1 ---
    if (t < H_) {
        float pre = b0[z * H_ + t];
        #pragma unroll 8
        for (int q = 0; q < Q_; ++q) pre += desc_s[q] * W0s[q * 129 + t];
        float hv = tanhf(pre) * am;     // mask applied BEFORE dtanh (matches ref)
        float dt = 1.0f - hv * hv;
        deda_s[t] = dt * W1[z * H_ + t];
    }
    // --- phase 2 (wave 2): minimum-image rij^2 * mask, independent of MLP ---
    if (t >= 128 && t < 128 + M_) {
        int m = t - 128;
        float b00 = box[0], b01 = box[1], b02 = box[2];
        float b10 = box[3], b11 = box[4], b12 = box[5];
        float b20 = box[6], b21 = box[7], b22 = box[8];
        // inverse via adjugate
        float c00 =   b11 * b22 - b12 * b21;
        float c01 = -(b10 * b22 - b12 * b20);
        float c02 =   b10 * b21 - b11 * b20;
        float det = b00 * c00 + b01 * c01 + b02 * c02;
        float id  = 1.0f / det;
        float i00 = c00 * id;
        float i10 = c01 * id;
        float i20 = c02 * id;
        float i01 = -(b01 * b22 - b02 * b21) * id;
        float i11 =  (b00 * b22 - b02 * b20) * id;
        float i21 = -(b00 * b21 - b01 * b20) * id;
        float i02 =  (b01 * b12 - b02 * b11) * id;
        float i12 = -(b00 * b12 - b02 * b10) * id;
        float i22 =  (b00 * b11 - b01 * b10) * id;

        int j = gidx[n * M_ + m];
        float dx = pos[j * 3 + 0] - pos[n * 3 + 0];
        float dy = pos[j * 3 + 1] - pos[n * 3 + 1];
        float dz = pos[j * 3 + 2] - pos[n * 3 + 2];
        // frac = dr @ inv_box
        float fx = dx * i00 + dy * i10 + dz * i20;
        float fy = dx * i01 + dy * i11 + dz * i21;
        float fz = dx * i02 + dy * i12 + dz * i22;
        fx -= rintf(fx); fy -= rintf(fy); fz -= rintf(fz);   // jnp.round = half-even
        // dr = frac @ box
        float rx = fx * b00 + fy * b10 + fz * b20;
        float ry = fx * b01 + fy * b11 + fz * b21;
        float rz = fx * b02 + fy * b12 + fz * b22;
        rij2m_s[m] = (rx * rx + ry * ry + rz * rz) * nmask[n * M_ + m];
    }
    __syncthreads();

    // --- phase 3: de_dq[q] = sum_h de_da[h] * W0[q][h] ---
    if (t < Q_) {
        float v = 0.0f;
        #pragma unroll 8
        for (int h = 0; h < H_; ++h) v += deda_s[h] * W0s[t * 129 + h];
        dedq_s[t] = v;
    }
    __syncthreads();

    // --- phase 4: the heavy stream. row r = m*3+c = t, 192 rows of 64 f32 ---
    if (t < 3 * M_) {
        int m = t / 3, c = t % 3;
        const float4* g4 = (const float4*)(grad + (((size_t)n * M_ + m) * 3 + c) * Q_);
        const float4* d4 = (const float4*)dedq_s;
        float s = 0.0f;
        #pragma unroll
        for (int j = 0; j < 16; ++j) {
            float4 g = g4[j];
            float4 d = d4[j];    // LDS broadcast (same addr across lanes) = free
            s += g.x * d.x + g.y * d.y + g.z * d.z + g.w * d.w;
        }
        float nm = nmask[n * M_ + m];          // force mask
        cred[c][m] = -rij2m_s[m] * (s * nm);   // dipole contribution
    }
    __syncthreads();

    // --- deterministic per-block reduce (3 serial 64-sums, fixed order) ---
    if (t < 3) {
        float s = 0.0f;
        #pragma unroll
        for (int m = 0; m < M_; ++m) s += cred[t][m];
        partials[n * 3 + t] = s;
    }
}

// ---------------------------------------------------------------------------
// Kernel 2: deterministic reduction of partials[A][3] -> out[3]
// ---------------------------------------------------------------------------
__global__ __launch_bounds__(256) void tnep_reduce(
    const float* __restrict__ partials, float* __restrict__ out)
{
    __shared__ float sbuf[256];
    const int t = threadIdx.x;
    for (int c = 0; c < 3; ++c) {
        float s = 0.0f;
        for (int i = t; i < A_; i += 256) s += partials[i * 3 + c];
        sbuf[t] = s;
        __syncthreads();
        for (int off = 128; off > 0; off >>= 1) {
            if (t < off) sbuf[t] += sbuf[t + off];
            __syncthreads();
        }
        if (t == 0) out[c] = sbuf[0];
        __syncthreads();
    }
}

extern "C" void kernel_launch(void* const* d_in, const int* in_sizes, int n_in,
                              void* d_out, int out_size, void* d_ws, size_t ws_size,
                              hipStream_t stream) {
    const float* desc  = (const float*)d_in[0];
    const float* grad  = (const float*)d_in[1];
    const int*   gidx  = (const int*)  d_in[2];
    const float* pos   = (const float*)d_in[3];
    const int*   Zt    = (const int*)  d_in[4];
    const float* box   = (const float*)d_in[5];
    const float* amask = (const float*)d_in[6];
    const float* nmask = (const float*)d_in[7];
    const float* W0    = (const float*)d_in[8];
    const float* b0    = (const float*)d_in[9];
    const float* W1    = (const float*)d_in[10];
    // d_in[11] = b1 (unused by the dipole output)

    float* partials = (float*)d_ws;      // A*3 floats = 48 KB
    float* out      = (float*)d_out;     // 3 floats

    tnep_main<<<A_, 256, 0, stream>>>(desc, grad, gidx, pos, Zt, box,
                                      amask, nmask, W0, b0, W1, partials);
    tnep_reduce<<<1, 256, 0, stream>>>(partials, out);
}

// Round 2
// 50.623 us; speedup vs baseline: 1.1999x; 1.1999x over previous
//
#include <hip/hip_runtime.h>

#define A_ 4096
#define M_ 64
#define Q_ 64
#define H_ 128

// ---------------------------------------------------------------------------
// Kernel 1: one block (256 thr) per atom.
//   * 12x float4 register prefetch of the whole 48KB gradient block, issued
//     BEFORE any sync -> MLP runs under the stream (issue-early/consume-late)
//   * W0[Z[n]] staged to LDS stride 129 (conflict-free both orientations)
//   * forward MLP on waves 0-1, minimum-image coef on wave 2 (parallel)
//   * backward de_dq parallelized over all 256 threads (4-way h split)
//   * element-separable dipole accumulation: each grad element (m,c,q)
//     contributes coef[m]*g*dedq[q] to acc[c]; deterministic LDS tree
// ---------------------------------------------------------------------------
__global__ __launch_bounds__(256) void tnep_main(
    const float* __restrict__ desc,     // [A,Q]
    const float* __restrict__ grad,     // [A,M,3,Q]
    const int*   __restrict__ gidx,     // [A,M]
    const float* __restrict__ pos,      // [A,3]
    const int*   __restrict__ Zt,       // [A]
    const float* __restrict__ box,      // [3,3]
    const float* __restrict__ amask,    // [A]
    const float* __restrict__ nmask,    // [A,M]
    const float* __restrict__ W0,       // [NT,Q,H]
    const float* __restrict__ b0,       // [NT,H]
    const float* __restrict__ W1,       // [NT,H]
    float* __restrict__ partials)       // [3][A]  c-major
{
    __shared__ __align__(16) float W0s[Q_ * 129];
    __shared__ __align__(16) float desc_s[Q_];
    __shared__ float deda_s[H_];
    __shared__ __align__(16) float psum_s[256];     // backward partials [q][part]
    __shared__ __align__(16) float dedq_s[Q_];
    __shared__ float coef_s[M_];                    // -rij2*nmask*nmask
    __shared__ float red_s[3][256];

    const int n = blockIdx.x;
    const int t = threadIdx.x;

    // ---- phase 0: issue the full gradient-block prefetch FIRST (48KB) ----
    const float4* gbase = (const float4*)(grad + (size_t)n * (M_ * 3 * Q_));
    float4 gpre[12];
    #pragma unroll
    for (int k = 0; k < 12; ++k) gpre[k] = gbase[k * 256 + t];

    const int z = Zt[n];
    const float am = amask[n];

    // ---- phase 1: stage W0[z] -> LDS (padded 129), coalesced ----
    const float* W0z = W0 + (size_t)z * (Q_ * H_);
    #pragma unroll
    for (int idx = t; idx < Q_ * H_; idx += 256) {
        int q = idx >> 7;
        int h = idx & 127;
        W0s[q * 129 + h] = W0z[idx];
    }
    if (t < Q_) desc_s[t] = desc[n * Q_ + t];
    __syncthreads();

    // ---- phase 2a (waves 0,1): forward MLP -> de_da ----
    if (t < H_) {
        float pre = b0[z * H_ + t];
        #pragma unroll 8
        for (int q = 0; q < Q_; ++q) pre += desc_s[q] * W0s[q * 129 + t];
        float hv = tanhf(pre) * am;
        float dt = 1.0f - hv * hv;
        deda_s[t] = dt * W1[z * H_ + t];
    }
    // ---- phase 2b (wave 2): minimum-image coef[m] = -rij2*mask^2 ----
    if (t >= 128 && t < 128 + M_) {
        int m = t - 128;
        float b00 = box[0], b01 = box[1], b02 = box[2];
        float b10 = box[3], b11 = box[4], b12 = box[5];
        float b20 = box[6], b21 = box[7], b22 = box[8];
        float c00 =   b11 * b22 - b12 * b21;
        float c01 = -(b10 * b22 - b12 * b20);
        float c02 =   b10 * b21 - b11 * b20;
        float det = b00 * c00 + b01 * c01 + b02 * c02;
        float id  = 1.0f / det;
        float i00 = c00 * id;
        float i10 = c01 * id;
        float i20 = c02 * id;
        float i01 = -(b01 * b22 - b02 * b21) * id;
        float i11 =  (b00 * b22 - b02 * b20) * id;
        float i21 = -(b00 * b21 - b01 * b20) * id;
        float i02 =  (b01 * b12 - b02 * b11) * id;
        float i12 = -(b00 * b12 - b02 * b10) * id;
        float i22 =  (b00 * b11 - b01 * b10) * id;

        int j = gidx[n * M_ + m];
        float dx = pos[j * 3 + 0] - pos[n * 3 + 0];
        float dy = pos[j * 3 + 1] - pos[n * 3 + 1];
        float dz = pos[j * 3 + 2] - pos[n * 3 + 2];
        float fx = dx * i00 + dy * i10 + dz * i20;
        float fy = dx * i01 + dy * i11 + dz * i21;
        float fz = dx * i02 + dy * i12 + dz * i22;
        fx -= rintf(fx); fy -= rintf(fy); fz -= rintf(fz);
        float rx = fx * b00 + fy * b10 + fz * b20;
        float ry = fx * b01 + fy * b11 + fz * b21;
        float rz = fx * b02 + fy * b12 + fz * b22;
        float nm = nmask[n * M_ + m];
        coef_s[m] = -((rx * rx + ry * ry + rz * rz) * nm) * nm;
    }
    __syncthreads();

    // ---- phase 3: backward de_dq, all 256 threads (q = t>>2, part = t&3) ----
    {
        int q = t >> 2, part = t & 3;
        float v = 0.0f;
        #pragma unroll 8
        for (int i = 0; i < 32; ++i) {
            int h = part + 4 * i;                  // stride-4: banks stay spread
            v += deda_s[h] * W0s[q * 129 + h];
        }
        psum_s[t] = v;                             // layout [q][part]
    }
    __syncthreads();
    if (t < Q_) {
        float4 p = ((const float4*)psum_s)[t];
        dedq_s[t] = (p.x + p.y) + (p.z + p.w);
    }
    __syncthreads();

    // ---- phase 4: consume prefetched gradients, element-separable ----
    float acc0 = 0.0f, acc1 = 0.0f, acc2 = 0.0f;
    const float4* dq4 = (const float4*)dedq_s;
    const int q4 = t & 15;
    #pragma unroll
    for (int k = 0; k < 12; ++k) {
        int row = k * 16 + (t >> 4);               // 0..191 = m*3+c
        int m = row / 3;
        int c = row - 3 * m;
        float4 g = gpre[k];
        float4 d = dq4[q4];
        float p = (g.x * d.x + g.y * d.y + g.z * d.z + g.w * d.w) * coef_s[m];
        acc0 += (c == 0) ? p : 0.0f;
        acc1 += (c == 1) ? p : 0.0f;
        acc2 += (c == 2) ? p : 0.0f;
    }
    red_s[0][t] = acc0;
    red_s[1][t] = acc1;
    red_s[2][t] = acc2;
    __syncthreads();

    // ---- deterministic block tree reduce ----
    #pragma unroll
    for (int off = 128; off > 0; off >>= 1) {
        if (t < off) {
            red_s[0][t] += red_s[0][t + off];
            red_s[1][t] += red_s[1][t + off];
            red_s[2][t] += red_s[2][t + off];
        }
        __syncthreads();
    }
    if (t < 3) partials[t * A_ + n] = red_s[t][0];
}

// ---------------------------------------------------------------------------
// Kernel 2: deterministic reduction of partials[3][A] -> out[3]
// ---------------------------------------------------------------------------
__global__ __launch_bounds__(256) void tnep_reduce(
    const float* __restrict__ partials, float* __restrict__ out)
{
    __shared__ float sb[3][256];
    const int t = threadIdx.x;
    const float4* p0 = (const float4*)(partials);
    const float4* p1 = (const float4*)(partials + A_);
    const float4* p2 = (const float4*)(partials + 2 * A_);
    float s0 = 0.0f, s1 = 0.0f, s2 = 0.0f;
    #pragma unroll
    for (int i = 0; i < 4; ++i) {
        float4 a = p0[i * 256 + t]; s0 += (a.x + a.y) + (a.z + a.w);
        float4 b = p1[i * 256 + t]; s1 += (b.x + b.y) + (b.z + b.w);
        float4 c = p2[i * 256 + t]; s2 += (c.x + c.y) + (c.z + c.w);
    }
    sb[0][t] = s0; sb[1][t] = s1; sb[2][t] = s2;
    __syncthreads();
    #pragma unroll
    for (int off = 128; off > 0; off >>= 1) {
        if (t < off) {
            sb[0][t] += sb[0][t + off];
            sb[1][t] += sb[1][t + off];
            sb[2][t] += sb[2][t + off];
        }
        __syncthreads();
    }
    if (t < 3) out[t] = sb[t][0];
}

extern "C" void kernel_launch(void* const* d_in, const int* in_sizes, int n_in,
                              void* d_out, int out_size, void* d_ws, size_t ws_size,
                              hipStream_t stream) {
    const float* desc  = (const float*)d_in[0];
    const float* grad  = (const float*)d_in[1];
    const int*   gidx  = (const int*)  d_in[2];
    const float* pos   = (const float*)d_in[3];
    const int*   Zt    = (const int*)  d_in[4];
    const float* box   = (const float*)d_in[5];
    const float* amask = (const float*)d_in[6];
    const float* nmask = (const float*)d_in[7];
    const float* W0    = (const float*)d_in[8];
    const float* b0    = (const float*)d_in[9];
    const float* W1    = (const float*)d_in[10];
    // d_in[11] = b1 (unused for the dipole output)

    float* partials = (float*)d_ws;      // [3][A] floats = 48 KB
    float* out      = (float*)d_out;     // 3 floats

    tnep_main<<<A_, 256, 0, stream>>>(desc, grad, gidx, pos, Zt, box,
                                      amask, nmask, W0, b0, W1, partials);
    tnep_reduce<<<1, 256, 0, stream>>>(partials, out);
}